// Round 13
// baseline (1403.853 us; speedup 1.0000x reference)
//
#include <hip/hip_runtime.h>
#include <hip/hip_fp16.h>

#define N_NODES 100000
#define N_EDGES 3200000
#define BSHIFT 7
#define BSIZE 128
#define NB ((N_NODES + BSIZE - 1) / BSIZE)     // 782 buckets of 128 nodes
#define ROWBITS 17
#define ROWMASK ((1 << ROWBITS) - 1)
#define EPB 8192
#define NBLOCKS ((N_EDGES + EPB - 1) / EPB)    // 391 scatter blocks

// ---------------- edge_index dtype detect ----------------

__global__ void k_detect(const unsigned* __restrict__ w, int* __restrict__ flag) {
    __shared__ unsigned s[256];
    unsigned v = 0;
    for (int t = threadIdx.x; t < 4096; t += 256) v |= w[2 * t + 1];
    s[threadIdx.x] = v;
    __syncthreads();
    for (int off = 128; off > 0; off >>= 1) {
        if (threadIdx.x < (unsigned)off) s[threadIdx.x] |= s[threadIdx.x + off];
        __syncthreads();
    }
    if (threadIdx.x == 0) flag[0] = (s[0] == 0) ? 1 : 0;  // 1 => int64 layout
}

__device__ __forceinline__ void load_edge(const unsigned* __restrict__ e, int f, int E,
                                          int i, int& r, int& c) {
    if (f) { r = (int)e[2 * i]; c = (int)e[2 * E + 2 * i]; }
    else   { r = (int)e[i];     c = (int)e[E + i]; }
}

// ---------------- stage 1: per-block LDS bucket sort, sequential writes ----------------

__global__ __launch_bounds__(512) void k_scatter(const unsigned* __restrict__ eidx,
                                                 const int* __restrict__ flag,
                                                 const float* __restrict__ ew,
                                                 int2* __restrict__ staged,
                                                 int* __restrict__ cntT,
                                                 int* __restrict__ offT, int E, int n) {
    __shared__ int2 se[EPB];        // 64 KB
    __shared__ int  hist[NB];
    __shared__ int  bpos[NB];
    __shared__ int  s2[512];
    int tid = threadIdx.x;
    int blk = blockIdx.x;
    for (int i = tid; i < NB; i += 512) hist[i] = 0;
    __syncthreads();
    int f = flag[0];
    int base = blk * EPB;
    int lim = min(EPB, E - base);
    int rr[16], cc[16];
    float wv[16];
#pragma unroll
    for (int k = 0; k < 16; ++k) {
        int i = k * 512 + tid;
        rr[k] = -1; cc[k] = 0; wv[k] = 0.f;
        if (i < lim) {
            int r, c;
            load_edge(eidx, f, E, base + i, r, c);
            if ((unsigned)r < (unsigned)n && (unsigned)c < (unsigned)n) {
                rr[k] = r; cc[k] = c; wv[k] = ew[base + i];
            }
        }
    }
#pragma unroll
    for (int k = 0; k < 16; ++k)
        if (rr[k] >= 0) atomicAdd(&hist[cc[k] >> BSHIFT], 1);
    __syncthreads();
    int c0 = (2 * tid < NB) ? hist[2 * tid] : 0;
    int c1 = (2 * tid + 1 < NB) ? hist[2 * tid + 1] : 0;
    s2[tid] = c0 + c1;
    __syncthreads();
    for (int o = 1; o < 512; o <<= 1) {
        int t = (tid >= o) ? s2[tid - o] : 0;
        __syncthreads();
        s2[tid] += t;
        __syncthreads();
    }
    int cbase = s2[tid] - (c0 + c1);
    if (2 * tid < NB) bpos[2 * tid] = cbase;
    if (2 * tid + 1 < NB) bpos[2 * tid + 1] = cbase + c0;
    __syncthreads();
    for (int b = tid; b < NB; b += 512) {
        cntT[(size_t)blk * NB + b] = hist[b];
        offT[(size_t)blk * NB + b] = bpos[b];
    }
    __syncthreads();
#pragma unroll
    for (int k = 0; k < 16; ++k) {
        if (rr[k] >= 0) {
            int b = cc[k] >> BSHIFT, off = cc[k] & (BSIZE - 1);
            int pos = atomicAdd(&bpos[b], 1);
            se[pos] = make_int2((off << ROWBITS) | rr[k], __float_as_int(wv[k]));
        }
    }
    __syncthreads();
    for (int i = tid; i < lim; i += 512)
        staged[(size_t)blk * EPB + i] = se[i];
}

// ---------------- shared helper: load run tables + prefix scan (per bucket) ----------------
// rdst[j] = exclusive prefix of run lengths; rsrc[j] = run start in staged.

__device__ __forceinline__ int bucket_tables(const int* __restrict__ cntT,
                                             const int* __restrict__ offT,
                                             int b, int* rdst, int* rsrc, int* s2) {
    int tid = threadIdx.x;
    int c0 = 0, c1 = 0;
    int j0 = 2 * tid, j1 = 2 * tid + 1;
    if (j0 < NBLOCKS) { c0 = cntT[(size_t)j0 * NB + b]; rsrc[j0] = j0 * EPB + offT[(size_t)j0 * NB + b]; }
    if (j1 < NBLOCKS) { c1 = cntT[(size_t)j1 * NB + b]; rsrc[j1] = j1 * EPB + offT[(size_t)j1 * NB + b]; }
    s2[tid] = c0 + c1;
    __syncthreads();
    for (int o = 1; o < 256; o <<= 1) {
        int t = (tid >= o) ? s2[tid - o] : 0;
        __syncthreads();
        s2[tid] += t;
        __syncthreads();
    }
    int cbase = s2[tid] - (c0 + c1);
    if (j0 < NBLOCKS) rdst[j0] = cbase;
    if (j1 < NBLOCKS) rdst[j1] = cbase + c0;
    if (tid == 255) rdst[NBLOCKS] = s2[255];
    __syncthreads();
    return rdst[NBLOCKS];
}

__device__ __forceinline__ int run_search(const int* __restrict__ rdst, int d) {
    int lo = 0, hi = NBLOCKS;
    while (hi - lo > 1) {
        int mid = (lo + hi) >> 1;
        if (rdst[mid] <= d) lo = mid; else hi = mid;
    }
    return lo;
}

// ---------------- dinv: per-bucket weight sums via flat run walk ----------------

__global__ __launch_bounds__(256) void k_dinv(const int2* __restrict__ staged,
                                              const int* __restrict__ cntT,
                                              const int* __restrict__ offT,
                                              float* __restrict__ dinv, int n) {
    __shared__ int   rdst[NBLOCKS + 1];
    __shared__ int   rsrc[NBLOCKS];
    __shared__ int   s2[256];
    __shared__ float wsm[BSIZE];
    int tid = threadIdx.x;
    int b = blockIdx.x;
    int n0 = b << BSHIFT;
    int nn = min(BSIZE, n - n0);
    if (tid < BSIZE) wsm[tid] = 0.f;
    int cntE = bucket_tables(cntT, offT, b, rdst, rsrc, s2);
    for (int d = tid; d < cntE; d += 256) {
        int lo = run_search(rdst, d);
        int2 kv = staged[(size_t)rsrc[lo] + (d - rdst[lo])];
        atomicAdd(&wsm[kv.x >> ROWBITS], __int_as_float(kv.y));
    }
    __syncthreads();
    if (tid < nn) dinv[n0 + tid] = 1.0f / sqrtf(1.0f + wsm[tid]);
}

// ---------------- layer 1 transform: g1 = fp16(dinv * (x @ W1)) ----------------

__global__ __launch_bounds__(256) void k_gemm1(const float* __restrict__ x,
                                               const float* __restrict__ W1,
                                               const float* __restrict__ dinv,
                                               __half* __restrict__ g1, int n) {
    __shared__ float W1s[128 * 32];
    __shared__ float xs[8][128];
    int tid = threadIdx.x;
    for (int i = tid; i < 1024; i += 256)
        *reinterpret_cast<float4*>(W1s + 4 * i) = reinterpret_cast<const float4*>(W1)[i];
    int node0 = blockIdx.x * 8;
    {
        int ln = tid >> 5, ii = tid & 31;
        int node = node0 + ln;
        float4 vv = make_float4(0.f, 0.f, 0.f, 0.f);
        if (node < n) vv = reinterpret_cast<const float4*>(x)[node * 32 + ii];
        *reinterpret_cast<float4*>(&xs[ln][4 * ii]) = vv;
    }
    __syncthreads();
    int ln = tid >> 5;
    int kk = tid & 31;
    int node = node0 + ln;
    if (node < n) {
        float acc = 0.f;
#pragma unroll
        for (int i = 0; i < 128; ++i) acc += xs[ln][i] * W1s[i * 32 + kk];
        g1[node * 32 + kk] = __float2half(dinv[node] * acc);
    }
}

// ---------------- layer 1 aggregate: per-bucket LDS accumulator ----------------
// 32 edge-groups x 8 lanes x 4 channels. acc rows padded to 33 (bank spread).

__global__ __launch_bounds__(256) void k_agg1(const int2* __restrict__ staged,
                                              const int* __restrict__ cntT,
                                              const int* __restrict__ offT,
                                              const __half* __restrict__ g,
                                              const float* __restrict__ dinv,
                                              const float* __restrict__ b1,
                                              float* __restrict__ h, int n) {
    __shared__ int   rdst[NBLOCKS + 1];
    __shared__ int   rsrc[NBLOCKS];
    __shared__ int   s2[256];
    __shared__ float acc[BSIZE][33];     // 16.9 KB
    int tid = threadIdx.x;
    int b = blockIdx.x;
    int n0 = b << BSHIFT;
    int nn = min(BSIZE, n - n0);
    for (int i = tid; i < BSIZE * 33; i += 256) (&acc[0][0])[i] = 0.f;
    int cntE = bucket_tables(cntT, offT, b, rdst, rsrc, s2);
    int grp = tid >> 3;      // 0..31
    int cg  = tid & 7;       // channels 4*cg..4*cg+3
    for (int d = grp; d < cntE; d += 32) {
        int lo = run_search(rdst, d);
        int2 kv = staged[(size_t)rsrc[lo] + (d - rdst[lo])];
        int off = kv.x >> ROWBITS;
        int row = kv.x & ROWMASK;
        float w = __int_as_float(kv.y);
        float2 raw = *reinterpret_cast<const float2*>(g + ((size_t)row << 5) + (cg << 2));
        __half2 h01 = *reinterpret_cast<const __half2*>(&raw.x);
        __half2 h23 = *reinterpret_cast<const __half2*>(&raw.y);
        float2 f01 = __half22float2(h01), f23 = __half22float2(h23);
        atomicAdd(&acc[off][(cg << 2) + 0], w * f01.x);
        atomicAdd(&acc[off][(cg << 2) + 1], w * f01.y);
        atomicAdd(&acc[off][(cg << 2) + 2], w * f23.x);
        atomicAdd(&acc[off][(cg << 2) + 3], w * f23.y);
    }
    __syncthreads();
    // fused epilogue: self-loop + dinv + bias + leaky, coalesced h1 write
    for (int idx = tid; idx < nn * 32; idx += 256) {
        int node = idx >> 5, k = idx & 31;
        float self = __half2float(g[((size_t)(n0 + node) << 5) + k]);
        float di = dinv[n0 + node];
        float v = di * (acc[node][k] + self) + b1[k];
        v = v > 0.f ? v : 0.01f * v;
        h[((size_t)(n0 + node) << 5) + k] = v;
    }
}

// ---------------- layer 2 transform: g2 = fp16(dinv * (h1 @ W2)) ----------------

__global__ __launch_bounds__(256) void k_gemm2(const float* __restrict__ h1,
                                               const float* __restrict__ W2,
                                               const float* __restrict__ dinv,
                                               __half* __restrict__ g2, int n) {
    __shared__ float W2s[32 * 16];
    int tid = threadIdx.x;
    for (int i = tid; i < 32 * 16; i += 256) W2s[i] = W2[i];
    __syncthreads();
    int t = blockIdx.x * 256 + tid;
    if (t < n * 16) {
        int node = t >> 4, j = t & 15;
        float acc = 0.f;
#pragma unroll
        for (int k = 0; k < 32; ++k) acc += h1[node * 32 + k] * W2s[k * 16 + j];
        g2[t] = __float2half(dinv[node] * acc);
    }
}

// ---------------- layer 2 aggregate + fc: per-bucket LDS accumulator ----------------
// 64 edge-groups x 4 lanes x 4 channels. acc rows padded to 17.

__global__ __launch_bounds__(256) void k_agg2(const int2* __restrict__ staged,
                                              const int* __restrict__ cntT,
                                              const int* __restrict__ offT,
                                              const __half* __restrict__ g2,
                                              const float* __restrict__ dinv,
                                              const float* __restrict__ b2,
                                              const float* __restrict__ Wfc,
                                              const float* __restrict__ bfc,
                                              float* __restrict__ out, int n) {
    __shared__ int   rdst[NBLOCKS + 1];
    __shared__ int   rsrc[NBLOCKS];
    __shared__ int   s2[256];
    __shared__ float acc[BSIZE][17];     // 8.7 KB
    int tid = threadIdx.x;
    int b = blockIdx.x;
    int n0 = b << BSHIFT;
    int nn = min(BSIZE, n - n0);
    for (int i = tid; i < BSIZE * 17; i += 256) (&acc[0][0])[i] = 0.f;
    int cntE = bucket_tables(cntT, offT, b, rdst, rsrc, s2);
    int grp = tid >> 2;      // 0..63
    int cg  = tid & 3;       // channels 4*cg..4*cg+3
    for (int d = grp; d < cntE; d += 64) {
        int lo = run_search(rdst, d);
        int2 kv = staged[(size_t)rsrc[lo] + (d - rdst[lo])];
        int off = kv.x >> ROWBITS;
        int row = kv.x & ROWMASK;
        float w = __int_as_float(kv.y);
        float2 raw = *reinterpret_cast<const float2*>(g2 + ((size_t)row << 4) + (cg << 2));
        __half2 h01 = *reinterpret_cast<const __half2*>(&raw.x);
        __half2 h23 = *reinterpret_cast<const __half2*>(&raw.y);
        float2 f01 = __half22float2(h01), f23 = __half22float2(h23);
        atomicAdd(&acc[off][(cg << 2) + 0], w * f01.x);
        atomicAdd(&acc[off][(cg << 2) + 1], w * f01.y);
        atomicAdd(&acc[off][(cg << 2) + 2], w * f23.x);
        atomicAdd(&acc[off][(cg << 2) + 3], w * f23.y);
    }
    __syncthreads();
    // fused epilogue: self-loop + dinv + bias + leaky + fc dot
    if (tid < nn) {
        int node = tid;
        float di = dinv[n0 + node];
        float p = 0.f;
#pragma unroll
        for (int j = 0; j < 16; ++j) {
            float self = __half2float(g2[((size_t)(n0 + node) << 4) + j]);
            float v = di * (acc[node][j] + self) + b2[j];
            v = v > 0.f ? v : 0.01f * v;
            p += v * Wfc[j];
        }
        out[n0 + node] = p + bfc[0];
    }
}

extern "C" void kernel_launch(void* const* d_in, const int* in_sizes, int n_in,
                              void* d_out, int out_size, void* d_ws, size_t ws_size,
                              hipStream_t stream) {
    const float*    x    = (const float*)d_in[0];
    const unsigned* eidx = (const unsigned*)d_in[1];
    const float*    ew   = (const float*)d_in[2];
    const float*    W1   = (const float*)d_in[3];
    const float*    b1   = (const float*)d_in[4];
    const float*    W2   = (const float*)d_in[5];
    const float*    b2   = (const float*)d_in[6];
    const float*    Wfc  = (const float*)d_in[7];
    const float*    bfc  = (const float*)d_in[8];
    float* out = (float*)d_out;

    const int N = N_NODES;
    const int E = N_EDGES;

    char* ws = (char*)d_ws;
    int*    flag   = (int*)ws;                             // 4 B
    float*  dinv   = (float*)(ws + 1024u * 1024);          // N floats (400 KB)
    int*    cntT   = (int*)(ws + 1536u * 1024);            // NBLOCKS*NB ints (1.22 MB)
    int*    offT   = (int*)(ws + 2816u * 1024);            // NBLOCKS*NB ints (1.22 MB)
    int2*   staged = (int2*)(ws + 4u * 1024 * 1024);       // NBLOCKS*EPB int2 (25.7 MB), live to agg2
    __half* g1h    = (__half*)(ws + 30u * 1024 * 1024);    // N*32 half (6.4 MB)
    float*  h1     = (float*)(ws + 37u * 1024 * 1024);     // N*32 float (12.8 MB)
    __half* g2h    = (__half*)(ws + 50u * 1024 * 1024);    // N*16 half (3.2 MB)

    k_detect<<<1, 256, 0, stream>>>(eidx, flag);

    // --- CSR-lite build: bucket-grouped runs only (no per-node sort) ---
    k_scatter<<<NBLOCKS, 512, 0, stream>>>(eidx, flag, ew, staged, cntT, offT, E, N);
    k_dinv<<<NB, 256, 0, stream>>>(staged, cntT, offT, dinv, N);

    // --- layer 1 ---
    k_gemm1<<<(N + 7) / 8, 256, 0, stream>>>(x, W1, dinv, g1h, N);
    k_agg1<<<NB, 256, 0, stream>>>(staged, cntT, offT, g1h, dinv, b1, h1, N);

    // --- layer 2 (+ fc fused) ---
    k_gemm2<<<(N * 16 + 255) / 256, 256, 0, stream>>>(h1, W2, dinv, g2h, N);
    k_agg2<<<NB, 256, 0, stream>>>(staged, cntT, offT, g2h, dinv, b2, Wfc, bfc, out, N);
}